// Round 1
// 2105.945 us; speedup vs baseline: 3.6670x; 3.6670x over previous
//
#include <hip/hip_runtime.h>
#include <math.h>

// Problem constants
#define S_LEN 2048
#define HDIM  2048
#define NHEADS 16
#define NKVH   8
#define HD     128
#define FFDIM  6144
#define EPSV   1e-6f

// ---------------------------------------------------------------------------
// bf16 split helpers (RNE)
// ---------------------------------------------------------------------------
__device__ __forceinline__ ushort f2bf(float f) {
    unsigned u = __float_as_uint(f);
    u += 0x7FFF + ((u >> 16) & 1);
    return (ushort)(u >> 16);
}
__device__ __forceinline__ float bf2f(ushort h) {
    return __uint_as_float(((unsigned)h) << 16);
}

typedef __attribute__((ext_vector_type(8))) short bf16x8;
typedef __attribute__((ext_vector_type(4))) float f32x4;

__device__ __forceinline__ void glds16(const void* g, void* l) {
    __builtin_amdgcn_global_load_lds(
        (const __attribute__((address_space(1))) void*)g,
        (__attribute__((address_space(3))) void*)l, 16, 0, 0);
}

// ---------------------------------------------------------------------------
// RMSNorm over rows of 2048 -> bf16 hi/lo split output
// ---------------------------------------------------------------------------
__global__ __launch_bounds__(256) void rmsnorm_split_k(const float* __restrict__ in,
                                                       const float* __restrict__ w,
                                                       ushort* __restrict__ oh,
                                                       ushort* __restrict__ ol) {
    int s = blockIdx.x;
    int tid = threadIdx.x;
    const float* row = in + (size_t)s * HDIM;
    float ss = 0.0f;
    for (int i = tid; i < HDIM; i += 256) {
        float v = row[i];
        ss += v * v;
    }
    __shared__ float red[256];
    red[tid] = ss;
    __syncthreads();
    for (int off = 128; off > 0; off >>= 1) {
        if (tid < off) red[tid] += red[tid + off];
        __syncthreads();
    }
    float r = rsqrtf(red[0] / (float)HDIM + EPSV);
    for (int i = tid; i < HDIM; i += 256) {
        float v = row[i] * r * w[i];
        ushort h = f2bf(v);
        oh[(size_t)s * HDIM + i] = h;
        ol[(size_t)s * HDIM + i] = f2bf(v - bf2f(h));
    }
}

// ---------------------------------------------------------------------------
// Elementwise fp32 -> bf16 hi/lo split
// ---------------------------------------------------------------------------
__global__ __launch_bounds__(256) void split_k(const float* __restrict__ in,
                                               ushort* __restrict__ oh,
                                               ushort* __restrict__ ol, int n) {
    int i = blockIdx.x * 256 + threadIdx.x;
    if (i < n) {
        float v = in[i];
        ushort h = f2bf(v);
        oh[i] = h;
        ol[i] = f2bf(v - bf2f(h));
    }
}

// ---------------------------------------------------------------------------
// Transpose + split: W[K][Ntot] (cols n0..n0+Nc) -> Th/Tl [Nc][K] bf16
// grid (Nc/64, K/64), 256 threads
// ---------------------------------------------------------------------------
__global__ __launch_bounds__(256) void transpose_split_k(const float* __restrict__ W,
                                                         ushort* __restrict__ Th,
                                                         ushort* __restrict__ Tl,
                                                         int K, int Ntot, int n0) {
    __shared__ float t[64][65];
    int tid = threadIdx.x;
    int nt = blockIdx.x * 64;
    int kt = blockIdx.y * 64;
#pragma unroll
    for (int p = 0; p < 4; ++p) {
        int idx = tid + p * 256;
        int kk = idx >> 4;
        int nn = (idx & 15) * 4;
        float4 v = *(const float4*)&W[(size_t)(kt + kk) * Ntot + n0 + nt + nn];
        t[nn + 0][kk] = v.x;
        t[nn + 1][kk] = v.y;
        t[nn + 2][kk] = v.z;
        t[nn + 3][kk] = v.w;
    }
    __syncthreads();
#pragma unroll
    for (int p = 0; p < 4; ++p) {
        int idx = tid + p * 256;
        int nn = idx >> 4;
        int kk = (idx & 15) * 4;
        ushort4 hv, lv;
        float a0 = t[nn][kk + 0], a1 = t[nn][kk + 1], a2 = t[nn][kk + 2], a3 = t[nn][kk + 3];
        hv.x = f2bf(a0); lv.x = f2bf(a0 - bf2f(hv.x));
        hv.y = f2bf(a1); lv.y = f2bf(a1 - bf2f(hv.y));
        hv.z = f2bf(a2); lv.z = f2bf(a2 - bf2f(hv.z));
        hv.w = f2bf(a3); lv.w = f2bf(a3 - bf2f(hv.w));
        size_t o = (size_t)(nt + nn) * K + kt + kk;
        *(ushort4*)&Th[o] = hv;
        *(ushort4*)&Tl[o] = lv;
    }
}

// ---------------------------------------------------------------------------
// bf16x3 compensated MFMA GEMM.
//   C[M][N] = (Ah+Al)[M][K] @ (Bh+Bl)^T[N][K]^T   (3 MFMA products, fp32 acc)
//   MODE 0: C = acc (+ res)          MODE 1: d = silu(g)*acc -> Dh/Dl bf16 split
// Tile: BM=64, BN=128, BK=32. 256 thr = 4 waves; wave covers 64x32 (4x2 frags).
// LDS 24 KB, linear layout, staged via global_load_lds width=16 (m97 pattern).
// ---------------------------------------------------------------------------
template <int MODE>
__global__ __launch_bounds__(256, 3) void gemm_bf16x3(
    const ushort* __restrict__ Ah, const ushort* __restrict__ Al,
    const ushort* __restrict__ Bh, const ushort* __restrict__ Bl,
    const float* res, const float* __restrict__ gbuf,
    float* C, ushort* __restrict__ Dh, ushort* __restrict__ Dl,
    int M, int N, int K) {
    __shared__ __align__(16) ushort sA[2 * 64 * 32];    // Ah tile | Al tile
    __shared__ __align__(16) ushort sB[2 * 128 * 32];   // Bh tile | Bl tile

    // bijective XCD swizzle (grid sizes are multiples of 8)
    unsigned nbx = gridDim.x;
    unsigned flat = blockIdx.y * nbx + blockIdx.x;
    unsigned cpx = (nbx * gridDim.y) >> 3;
    unsigned sflat = (flat & 7u) * cpx + (flat >> 3);
    int bx = (int)(sflat % nbx);
    int by = (int)(sflat / nbx);
    int bm = by * 64, bn = bx * 128;

    int tid = threadIdx.x;
    int lane = tid & 63, wave = tid >> 6;

    // staging: chunk = 16B; A tile 256 chunks (1/thr), B tile 512 (2/thr)
    int srow = tid >> 2;
    int sk = (tid & 3) * 8;
    const ushort* gAh = Ah + (size_t)(bm + srow) * K + sk;
    const ushort* gAl = Al + (size_t)(bm + srow) * K + sk;
    const ushort* gB0h = Bh + (size_t)(bn + srow) * K + sk;
    const ushort* gB0l = Bl + (size_t)(bn + srow) * K + sk;
    const ushort* gB1h = Bh + (size_t)(bn + 64 + srow) * K + sk;
    const ushort* gB1l = Bl + (size_t)(bn + 64 + srow) * K + sk;
    ushort* lAh = sA + tid * 8;
    ushort* lAl = sA + 2048 + tid * 8;
    ushort* lB0h = sB + tid * 8;
    ushort* lB1h = sB + 2048 + tid * 8;
    ushort* lB0l = sB + 4096 + tid * 8;
    ushort* lB1l = sB + 6144 + tid * 8;

    int r = lane & 15, kq = lane >> 4;
    const ushort* pA = sA + r * 32 + kq * 8;                 // + mi*512 (row mi*16+r)
    const ushort* pB = sB + (wave * 32 + r) * 32 + kq * 8;   // + ni*512

    f32x4 acc[4][2] = {};

    for (int k0 = 0; k0 < K; k0 += 32) {
        glds16(gAh, lAh);
        glds16(gAl, lAl);
        glds16(gB0h, lB0h);
        glds16(gB1h, lB1h);
        glds16(gB0l, lB0l);
        glds16(gB1l, lB1l);
        gAh += 32; gAl += 32; gB0h += 32; gB0l += 32; gB1h += 32; gB1l += 32;
        __syncthreads();   // vmcnt drained by compiler -> tiles resident

        bf16x8 ah[4], al[4], bh[2], bl[2];
#pragma unroll
        for (int mi = 0; mi < 4; ++mi) {
            ah[mi] = *(const bf16x8*)(pA + mi * 512);
            al[mi] = *(const bf16x8*)(pA + 2048 + mi * 512);
        }
#pragma unroll
        for (int ni = 0; ni < 2; ++ni) {
            bh[ni] = *(const bf16x8*)(pB + ni * 512);
            bl[ni] = *(const bf16x8*)(pB + 4096 + ni * 512);
        }
#pragma unroll
        for (int mi = 0; mi < 4; ++mi)
#pragma unroll
            for (int ni = 0; ni < 2; ++ni) {
                acc[mi][ni] = __builtin_amdgcn_mfma_f32_16x16x32_bf16(ah[mi], bh[ni], acc[mi][ni], 0, 0, 0);
                acc[mi][ni] = __builtin_amdgcn_mfma_f32_16x16x32_bf16(al[mi], bh[ni], acc[mi][ni], 0, 0, 0);
                acc[mi][ni] = __builtin_amdgcn_mfma_f32_16x16x32_bf16(ah[mi], bl[ni], acc[mi][ni], 0, 0, 0);
            }
        __syncthreads();   // all reads done before next stage overwrites
    }

    // epilogue; C/D layout: col = lane&15, row = (lane>>4)*4 + j  [m89-verified]
    int c0 = bn + wave * 32 + (lane & 15);
    int r0 = bm + (lane >> 4) * 4;
#pragma unroll
    for (int mi = 0; mi < 4; ++mi)
#pragma unroll
        for (int ni = 0; ni < 2; ++ni)
#pragma unroll
            for (int j = 0; j < 4; ++j) {
                int row = r0 + mi * 16 + j;
                int col = c0 + ni * 16;
                size_t idx = (size_t)row * N + col;
                float val = acc[mi][ni][j];
                if (MODE == 0) {
                    if (res) val += res[idx];
                    C[idx] = val;
                } else {
                    float gv = gbuf[idx];
                    float dv = gv / (1.0f + expf(-gv)) * val;
                    ushort hh = f2bf(dv);
                    Dh[idx] = hh;
                    Dl[idx] = f2bf(dv - bf2f(hh));
                }
            }
}

// ---------------------------------------------------------------------------
// Per-head RMSNorm (over HD=128) + RoPE, in place.
// ---------------------------------------------------------------------------
__global__ __launch_bounds__(128) void qk_norm_rope_k(float* __restrict__ qk,
                                                      const float* __restrict__ nw,
                                                      const int* __restrict__ positions,
                                                      int nheads) {
    int s = blockIdx.x;
    int h = blockIdx.y;
    int d = threadIdx.x;
    float* row = qk + ((size_t)s * nheads + h) * HD;
    __shared__ float buf[HD];
    __shared__ float red[HD];
    float v = row[d];
    red[d] = v * v;
    __syncthreads();
    for (int off = 64; off > 0; off >>= 1) {
        if (d < off) red[d] += red[d + off];
        __syncthreads();
    }
    float r = rsqrtf(red[0] / (float)HD + EPSV);
    float nv = v * r * nw[d];
    buf[d] = nv;
    __syncthreads();
    float pos = (float)positions[s];
    int d2 = d & 63;
    float inv_freq = expf(-((float)(2 * d2) / 128.0f) * 13.815510557964274f);
    float freq = pos * inv_freq;
    float c, sn;
    sincosf(freq, &sn, &c);
    float rot = (d < 64) ? -buf[d + 64] : buf[d - 64];
    row[d] = nv * c + rot * sn;
}

// ---------------------------------------------------------------------------
// Flash attention (unchanged from verified version)
// ---------------------------------------------------------------------------
#define TQ 32
#define TK 64

__global__ __launch_bounds__(256) void attn_flash_k(
    const float* __restrict__ q, const float* __restrict__ k,
    const float* __restrict__ v, const int* __restrict__ keys_idxs,
    const int* __restrict__ hs_idxs, float* __restrict__ ctx) {
    int bx = blockIdx.x;
    int qt = (bx & 1) ? (63 - (bx >> 1)) : (bx >> 1);
    int h = blockIdx.y;
    int kvh = h >> 1;
    int tid = threadIdx.x;
    int q0 = qt * TQ;
    const float scale = 0.088388347648318447f;

    __shared__ float Qs[TQ * 132];
    __shared__ float KV[128 * 68];
    __shared__ float Ps[TQ * 68];
    __shared__ int kidx[TK];
    __shared__ int qpos[TQ];

    int rg = tid >> 4;
    int cg = tid & 15;

#pragma unroll
    for (int p = 0; p < 4; ++p) {
        int idx = tid + p * 256;
        int rr = idx >> 5, d4 = (idx & 31) << 2;
        *(float4*)&Qs[rr * 132 + d4] =
            *(const float4*)&q[((size_t)(q0 + rr) * NHEADS + h) * HD + d4];
    }
    if (tid < TQ) qpos[tid] = hs_idxs[q0 + tid];

    float o_acc[2][8] = {};
    float m_run[2] = {-3.0e38f, -3.0e38f};
    float l_run[2] = {0.0f, 0.0f};

    __syncthreads();
    int hs_max = qpos[TQ - 1];

    for (int kt = 0; kt < S_LEN / TK; ++kt) {
        int k0 = kt * TK;
        if (keys_idxs[k0] > hs_max) break;
        __syncthreads();
#pragma unroll
        for (int p = 0; p < 8; ++p) {
            int idx = tid + p * 256;
            int rr = idx >> 5, d4 = (idx & 31) << 2;
            float4 kv4 = *(const float4*)&k[((size_t)(k0 + rr) * NKVH + kvh) * HD + d4];
            KV[(d4 + 0) * 68 + rr] = kv4.x;
            KV[(d4 + 1) * 68 + rr] = kv4.y;
            KV[(d4 + 2) * 68 + rr] = kv4.z;
            KV[(d4 + 3) * 68 + rr] = kv4.w;
        }
        if (tid < TK) kidx[tid] = keys_idxs[k0 + tid];
        __syncthreads();

        float s[2][4] = {};
#pragma unroll 8
        for (int d = 0; d < HD; d += 4) {
            float4 a0 = *(const float4*)&Qs[(2 * rg + 0) * 132 + d];
            float4 a1 = *(const float4*)&Qs[(2 * rg + 1) * 132 + d];
            float4 b0 = *(const float4*)&KV[(d + 0) * 68 + 4 * cg];
            float4 b1 = *(const float4*)&KV[(d + 1) * 68 + 4 * cg];
            float4 b2 = *(const float4*)&KV[(d + 2) * 68 + 4 * cg];
            float4 b3 = *(const float4*)&KV[(d + 3) * 68 + 4 * cg];
            float a[2][4] = {{a0.x, a0.y, a0.z, a0.w}, {a1.x, a1.y, a1.z, a1.w}};
            float b[4][4] = {{b0.x, b0.y, b0.z, b0.w}, {b1.x, b1.y, b1.z, b1.w},
                             {b2.x, b2.y, b2.z, b2.w}, {b3.x, b3.y, b3.z, b3.w}};
#pragma unroll
            for (int i = 0; i < 2; ++i)
#pragma unroll
                for (int dd = 0; dd < 4; ++dd)
#pragma unroll
                    for (int j = 0; j < 4; ++j)
                        s[i][j] += a[i][dd] * b[dd][j];
        }

        int kj[4];
#pragma unroll
        for (int j = 0; j < 4; ++j) kj[j] = kidx[4 * cg + j];
        float mx[2], mn[2], al2[2], rs[2];
#pragma unroll
        for (int i = 0; i < 2; ++i) {
            int pos = qpos[2 * rg + i];
            mx[i] = -3.0e38f;
#pragma unroll
            for (int j = 0; j < 4; ++j) {
                s[i][j] = s[i][j] * scale + ((kj[j] <= pos) ? 0.0f : -1.0e9f);
                mx[i] = fmaxf(mx[i], s[i][j]);
            }
        }
#pragma unroll
        for (int off = 1; off < 16; off <<= 1) {
            mx[0] = fmaxf(mx[0], __shfl_xor(mx[0], off));
            mx[1] = fmaxf(mx[1], __shfl_xor(mx[1], off));
        }
#pragma unroll
        for (int i = 0; i < 2; ++i) {
            mn[i] = fmaxf(m_run[i], mx[i]);
            al2[i] = __expf(m_run[i] - mn[i]);
            m_run[i] = mn[i];
            float4 pv;
            pv.x = __expf(s[i][0] - mn[i]);
            pv.y = __expf(s[i][1] - mn[i]);
            pv.z = __expf(s[i][2] - mn[i]);
            pv.w = __expf(s[i][3] - mn[i]);
            rs[i] = pv.x + pv.y + pv.z + pv.w;
            *(float4*)&Ps[(2 * rg + i) * 68 + 4 * cg] = pv;
        }
#pragma unroll
        for (int off = 1; off < 16; off <<= 1) {
            rs[0] += __shfl_xor(rs[0], off);
            rs[1] += __shfl_xor(rs[1], off);
        }
#pragma unroll
        for (int i = 0; i < 2; ++i) {
            l_run[i] = l_run[i] * al2[i] + rs[i];
#pragma unroll
            for (int j = 0; j < 8; ++j) o_acc[i][j] *= al2[i];
        }
        __syncthreads();
#pragma unroll
        for (int p = 0; p < 8; ++p) {
            int idx = tid + p * 256;
            int rr = idx >> 5, d4 = (idx & 31) << 2;
            *(float4*)&KV[rr * 132 + d4] =
                *(const float4*)&v[((size_t)(k0 + rr) * NKVH + kvh) * HD + d4];
        }
        __syncthreads();
#pragma unroll 8
        for (int kk = 0; kk < TK; kk += 4) {
            float4 p0 = *(const float4*)&Ps[(2 * rg + 0) * 68 + kk];
            float4 p1 = *(const float4*)&Ps[(2 * rg + 1) * 68 + kk];
            float pp[2][4] = {{p0.x, p0.y, p0.z, p0.w}, {p1.x, p1.y, p1.z, p1.w}};
#pragma unroll
            for (int dd = 0; dd < 4; ++dd) {
                float4 v0 = *(const float4*)&KV[(kk + dd) * 132 + 8 * cg];
                float4 v1 = *(const float4*)&KV[(kk + dd) * 132 + 8 * cg + 4];
                float vv[8] = {v0.x, v0.y, v0.z, v0.w, v1.x, v1.y, v1.z, v1.w};
#pragma unroll
                for (int i = 0; i < 2; ++i)
#pragma unroll
                    for (int j = 0; j < 8; ++j)
                        o_acc[i][j] += pp[i][dd] * vv[j];
            }
        }
    }
#pragma unroll
    for (int i = 0; i < 2; ++i) {
        float invl = 1.0f / l_run[i];
        float4 o0, o1;
        o0.x = o_acc[i][0] * invl; o0.y = o_acc[i][1] * invl;
        o0.z = o_acc[i][2] * invl; o0.w = o_acc[i][3] * invl;
        o1.x = o_acc[i][4] * invl; o1.y = o_acc[i][5] * invl;
        o1.z = o_acc[i][6] * invl; o1.w = o_acc[i][7] * invl;
        size_t base = ((size_t)(q0 + 2 * rg + i) * NHEADS + h) * HD + 8 * cg;
        *(float4*)&ctx[base] = o0;
        *(float4*)&ctx[base + 4] = o1;
    }
}

// ---------------------------------------------------------------------------
// Importance (unchanged)
// ---------------------------------------------------------------------------
__global__ __launch_bounds__(256) void importance_scores_k(const float* __restrict__ q,
                                                           const float* __restrict__ k,
                                                           float* __restrict__ imp_ws) {
    int h = blockIdx.x;
    int kv = h >> 1;
    int tid = threadIdx.x;
    __shared__ float qrow[HD];
    __shared__ float sc[S_LEN];
    __shared__ float red[256];
    const float* qp = q + ((size_t)(S_LEN - 1) * NHEADS + h) * HD;
    if (tid < HD) qrow[tid] = qp[tid];
    __syncthreads();
    const float scale = 0.088388347648318447f;
    float lmax = -3.0e38f;
#pragma unroll
    for (int rep = 0; rep < 8; ++rep) {
        int j = tid + rep * 256;
        const float* kp = k + ((size_t)j * NKVH + kv) * HD;
        float dot = 0.0f;
        for (int d = 0; d < HD; ++d) dot += qrow[d] * kp[d];
        float sval = dot * scale;
        sc[j] = sval;
        lmax = fmaxf(lmax, sval);
    }
    red[tid] = lmax;
    __syncthreads();
    for (int off = 128; off > 0; off >>= 1) {
        if (tid < off) red[tid] = fmaxf(red[tid], red[tid + off]);
        __syncthreads();
    }
    float m = red[0];
    __syncthreads();
    float lsum = 0.0f;
    float evals[8];
#pragma unroll
    for (int rep = 0; rep < 8; ++rep) {
        int j = tid + rep * 256;
        float e = expf(sc[j] - m);
        evals[rep] = e;
        lsum += e;
    }
    red[tid] = lsum;
    __syncthreads();
    for (int off = 128; off > 0; off >>= 1) {
        if (tid < off) red[tid] += red[tid + off];
        __syncthreads();
    }
    float inv = 1.0f / red[0];
#pragma unroll
    for (int rep = 0; rep < 8; ++rep) {
        int j = tid + rep * 256;
        imp_ws[(size_t)h * S_LEN + j] = evals[rep] * inv;
    }
}

__global__ __launch_bounds__(256) void importance_combine_k(const float* __restrict__ imp_ws,
                                                            float* __restrict__ out) {
    int j = blockIdx.x * 256 + threadIdx.x;
    float sum = 0.0f;
    for (int h = 0; h < NHEADS; ++h) sum += imp_ws[(size_t)h * S_LEN + j];
    out[j] = (j == S_LEN - 1) ? 3.0e38f : sum * (1.0f / NHEADS);
}

// ---------------------------------------------------------------------------
extern "C" void kernel_launch(void* const* d_in, const int* in_sizes, int n_in,
                              void* d_out, int out_size, void* d_ws, size_t ws_size,
                              hipStream_t stream) {
    const float* hidden    = (const float*)d_in[0];
    const int*   keys_idxs = (const int*)d_in[2];
    const int*   hs_idxs   = (const int*)d_in[3];
    const int*   positions = (const int*)d_in[4];
    const float* ln_in_w   = (const float*)d_in[5];
    const float* q_w       = (const float*)d_in[6];
    const float* k_w       = (const float*)d_in[7];
    const float* v_w       = (const float*)d_in[8];
    const float* q_norm_w  = (const float*)d_in[9];
    const float* k_norm_w  = (const float*)d_in[10];
    const float* o_w       = (const float*)d_in[11];
    const float* ln_post_w = (const float*)d_in[12];
    const float* gate_w    = (const float*)d_in[13];
    const float* up_w      = (const float*)d_in[14];
    const float* down_w    = (const float*)d_in[15];

    float* out = (float*)d_out;
    float* ws = (float*)d_ws;
    const size_t MF = 1024ull * 1024;   // 1M floats

    // Region plan (floats; total 20 MF = 80 MB, same peak as previous version):
    //  [0,4M)    Xh/Xl (bf16)      -> later: importance scratch
    //  [4M,8M)   weight split scratch Wh/Wl (bf16, up to 4M elems each)
    //  [8M,12M)  q fp32            -> later: ctx split Ch/Cl -> later: g chunk fp32
    //  [12M,14M) k fp32            \_ later: h fp32 -> later: D chunk split Dh/Dl
    //  [14M,16M) v fp32            /
    //  [16M,20M) ctx fp32          -> later: Yh/Yl (bf16)
    ushort* Xh = (ushort*)(ws);
    ushort* Xl = (ushort*)(ws + 2 * MF);
    ushort* Wh = (ushort*)(ws + 4 * MF);
    ushort* Wl = (ushort*)(ws + 6 * MF);
    float*  qb  = ws + 8 * MF;
    float*  kbf = ws + 12 * MF;
    float*  vbf = ws + 14 * MF;
    float*  ctx = ws + 16 * MF;
    float*  imp = ws;                       // X dead by importance time
    ushort* Ch = (ushort*)(ws + 8 * MF);
    ushort* Cl = (ushort*)(ws + 10 * MF);
    float*  hb = ws + 12 * MF;
    ushort* Yh = (ushort*)(ws + 16 * MF);
    ushort* Yl = (ushort*)(ws + 18 * MF);
    float*  gb = ws + 8 * MF;
    ushort* Dh = (ushort*)(ws + 12 * MF);
    ushort* Dl = (ushort*)(ws + 14 * MF);

    // 1. x = rms(hidden) -> bf16 split
    rmsnorm_split_k<<<S_LEN, 256, 0, stream>>>(hidden, ln_in_w, Xh, Xl);

    // 2. q/k/v projections (MFMA bf16x3)
    transpose_split_k<<<dim3(32, 32), 256, 0, stream>>>(q_w, Wh, Wl, HDIM, HDIM, 0);
    gemm_bf16x3<0><<<dim3(HDIM / 128, S_LEN / 64), 256, 0, stream>>>(
        Xh, Xl, Wh, Wl, nullptr, nullptr, qb, nullptr, nullptr, S_LEN, HDIM, HDIM);

    transpose_split_k<<<dim3(16, 32), 256, 0, stream>>>(k_w, Wh, Wl, HDIM, 1024, 0);
    gemm_bf16x3<0><<<dim3(1024 / 128, S_LEN / 64), 256, 0, stream>>>(
        Xh, Xl, Wh, Wl, nullptr, nullptr, kbf, nullptr, nullptr, S_LEN, 1024, HDIM);

    transpose_split_k<<<dim3(16, 32), 256, 0, stream>>>(v_w, Wh, Wl, HDIM, 1024, 0);
    gemm_bf16x3<0><<<dim3(1024 / 128, S_LEN / 64), 256, 0, stream>>>(
        Xh, Xl, Wh, Wl, nullptr, nullptr, vbf, nullptr, nullptr, S_LEN, 1024, HDIM);

    // 3. per-head norm + rope
    qk_norm_rope_k<<<dim3(S_LEN, NHEADS), 128, 0, stream>>>(qb, q_norm_w, positions, NHEADS);
    qk_norm_rope_k<<<dim3(S_LEN, NKVH), 128, 0, stream>>>(kbf, k_norm_w, positions, NKVH);

    // 4. flash attention -> ctx
    attn_flash_k<<<dim3(S_LEN / TQ, NHEADS), 256, 0, stream>>>(
        qb, kbf, vbf, keys_idxs, hs_idxs, ctx);

    // 5. importance (needs q,k; before their regions are reused)
    importance_scores_k<<<NHEADS, 256, 0, stream>>>(qb, kbf, imp);
    importance_combine_k<<<S_LEN / 256, 256, 0, stream>>>(imp, out + (size_t)S_LEN * HDIM);

    // 6. h = hidden + ctx @ o_w
    split_k<<<(S_LEN * HDIM) / 256, 256, 0, stream>>>(ctx, Ch, Cl, S_LEN * HDIM);
    transpose_split_k<<<dim3(32, 32), 256, 0, stream>>>(o_w, Wh, Wl, HDIM, HDIM, 0);
    gemm_bf16x3<0><<<dim3(HDIM / 128, S_LEN / 64), 256, 0, stream>>>(
        Ch, Cl, Wh, Wl, hidden, nullptr, hb, nullptr, nullptr, S_LEN, HDIM, HDIM);

    // 7. out = h (residual base for K-chunked down-proj accumulation)
    hipMemcpyAsync(out, hb, (size_t)S_LEN * HDIM * sizeof(float),
                   hipMemcpyDeviceToDevice, stream);

    // 8. y = rms(h) -> bf16 split
    rmsnorm_split_k<<<S_LEN, 256, 0, stream>>>(hb, ln_post_w, Yh, Yl);

    // 9. MLP in three FF-chunks of 2048: g = y@Wg_c ; d = silu(g)*(y@Wu_c)
    //    (fused epilogue, bf16-split output) ; out += d @ Wd_c
    for (int c = 0; c < 3; ++c) {
        transpose_split_k<<<dim3(32, 32), 256, 0, stream>>>(gate_w, Wh, Wl, HDIM, FFDIM, c * 2048);
        gemm_bf16x3<0><<<dim3(16, 32), 256, 0, stream>>>(
            Yh, Yl, Wh, Wl, nullptr, nullptr, gb, nullptr, nullptr, S_LEN, 2048, HDIM);
        transpose_split_k<<<dim3(32, 32), 256, 0, stream>>>(up_w, Wh, Wl, HDIM, FFDIM, c * 2048);
        gemm_bf16x3<1><<<dim3(16, 32), 256, 0, stream>>>(
            Yh, Yl, Wh, Wl, nullptr, gb, nullptr, Dh, Dl, S_LEN, 2048, HDIM);
        transpose_split_k<<<dim3(32, 32), 256, 0, stream>>>(
            down_w + (size_t)c * 2048 * HDIM, Wh, Wl, 2048, HDIM, 0);
        gemm_bf16x3<0><<<dim3(16, 32), 256, 0, stream>>>(
            Dh, Dl, Wh, Wl, out, nullptr, out, nullptr, nullptr, S_LEN, HDIM, 2048);
    }
}

// Round 2
// 1427.227 us; speedup vs baseline: 5.4108x; 1.4756x over previous
//
#include <hip/hip_runtime.h>
#include <math.h>

// Problem constants
#define S_LEN 2048
#define HDIM  2048
#define NHEADS 16
#define NKVH   8
#define HD     128
#define FFDIM  6144
#define EPSV   1e-6f

// ---------------------------------------------------------------------------
// bf16 split helpers
// ---------------------------------------------------------------------------
__device__ __forceinline__ ushort f2bf(float f) {   // RNE
    unsigned u = __float_as_uint(f);
    u += 0x7FFF + ((u >> 16) & 1);
    return (ushort)(u >> 16);
}
__device__ __forceinline__ float bf2f(ushort h) {
    return __uint_as_float(((unsigned)h) << 16);
}

typedef __attribute__((ext_vector_type(8))) short bf16x8;
typedef __attribute__((ext_vector_type(4))) float f32x4;

__device__ __forceinline__ void glds16(const void* g, void* l) {
    __builtin_amdgcn_global_load_lds(
        (const __attribute__((address_space(1))) void*)g,
        (__attribute__((address_space(3))) void*)l, 16, 0, 0);
}

// ---------------------------------------------------------------------------
// RMSNorm over rows of 2048 -> bf16 hi/lo split output
// ---------------------------------------------------------------------------
__global__ __launch_bounds__(256) void rmsnorm_split_k(const float* __restrict__ in,
                                                       const float* __restrict__ w,
                                                       ushort* __restrict__ oh,
                                                       ushort* __restrict__ ol) {
    int s = blockIdx.x;
    int tid = threadIdx.x;
    const float* row = in + (size_t)s * HDIM;
    float ss = 0.0f;
    for (int i = tid; i < HDIM; i += 256) {
        float v = row[i];
        ss += v * v;
    }
    __shared__ float red[256];
    red[tid] = ss;
    __syncthreads();
    for (int off = 128; off > 0; off >>= 1) {
        if (tid < off) red[tid] += red[tid + off];
        __syncthreads();
    }
    float r = rsqrtf(red[0] / (float)HDIM + EPSV);
    for (int i = tid; i < HDIM; i += 256) {
        float v = row[i] * r * w[i];
        ushort h = f2bf(v);
        oh[(size_t)s * HDIM + i] = h;
        ol[(size_t)s * HDIM + i] = f2bf(v - bf2f(h));
    }
}

// ---------------------------------------------------------------------------
// Elementwise fp32 -> bf16 hi/lo split
// ---------------------------------------------------------------------------
__global__ __launch_bounds__(256) void split_k(const float* __restrict__ in,
                                               ushort* __restrict__ oh,
                                               ushort* __restrict__ ol, int n) {
    int i = blockIdx.x * 256 + threadIdx.x;
    if (i < n) {
        float v = in[i];
        ushort h = f2bf(v);
        oh[i] = h;
        ol[i] = f2bf(v - bf2f(h));
    }
}

// ---------------------------------------------------------------------------
// K conversion: fp32 [S][NKVH][HD] -> bf16 hi/lo, d-index XOR-swizzled per row
// (d ^= (s&7)<<3) so linear glds16 staging yields a conflict-free LDS tile.
// ---------------------------------------------------------------------------
__global__ __launch_bounds__(256) void conv_k_swz_k(const float* __restrict__ in,
                                                    ushort* __restrict__ oh,
                                                    ushort* __restrict__ ol) {
    int i = blockIdx.x * 256 + threadIdx.x;      // over S*NKVH*HD = 2M
    int s = i >> 10;                              // NKVH*HD = 1024
    int d = i & 127;
    int base = i & ~127;
    float v = in[i];
    unsigned u = __float_as_uint(v);
    float hi = __uint_as_float(u & 0xFFFF0000u);
    int o = base + (d ^ ((s & 7) << 3));
    oh[o] = (ushort)(u >> 16);
    ol[o] = (ushort)(__float_as_uint(v - hi) >> 16);
}

// ---------------------------------------------------------------------------
// V conversion + transpose: fp32 [S][NKVH][HD] -> bf16 hi/lo [NKVH][HD][S],
// s-index XOR-swizzled within each 64-block (s ^= (d&7)<<3).
// grid (S/64, HD/64, NKVH), 256 thr.
// ---------------------------------------------------------------------------
__global__ __launch_bounds__(256) void conv_vt_k(const float* __restrict__ v,
                                                 ushort* __restrict__ oh,
                                                 ushort* __restrict__ ol) {
    __shared__ float t[64][65];
    int s0 = blockIdx.x * 64, d0 = blockIdx.y * 64, kvh = blockIdx.z;
    int tid = threadIdx.x;
#pragma unroll
    for (int p = 0; p < 4; ++p) {
        int c = tid + p * 256;
        int ss = c >> 4, d4 = (c & 15) * 4;
        float4 x = *(const float4*)&v[((size_t)(s0 + ss) * NKVH + kvh) * HD + d0 + d4];
        t[d4 + 0][ss] = x.x;
        t[d4 + 1][ss] = x.y;
        t[d4 + 2][ss] = x.z;
        t[d4 + 3][ss] = x.w;
    }
    __syncthreads();
#pragma unroll
    for (int p = 0; p < 4; ++p) {
        int c = tid + p * 256;
        int dd = c >> 4, s4 = (c & 15) * 4;
        int d = d0 + dd;
        int sx = s4 ^ ((d & 7) << 3);
        size_t obase = ((size_t)kvh * HD + d) * S_LEN + s0 + sx;
        ushort4 hv, lv;
        float a0 = t[dd][s4 + 0], a1 = t[dd][s4 + 1], a2 = t[dd][s4 + 2], a3 = t[dd][s4 + 3];
        unsigned u0 = __float_as_uint(a0), u1 = __float_as_uint(a1);
        unsigned u2 = __float_as_uint(a2), u3 = __float_as_uint(a3);
        hv.x = (ushort)(u0 >> 16); lv.x = (ushort)(__float_as_uint(a0 - __uint_as_float(u0 & 0xFFFF0000u)) >> 16);
        hv.y = (ushort)(u1 >> 16); lv.y = (ushort)(__float_as_uint(a1 - __uint_as_float(u1 & 0xFFFF0000u)) >> 16);
        hv.z = (ushort)(u2 >> 16); lv.z = (ushort)(__float_as_uint(a2 - __uint_as_float(u2 & 0xFFFF0000u)) >> 16);
        hv.w = (ushort)(u3 >> 16); lv.w = (ushort)(__float_as_uint(a3 - __uint_as_float(u3 & 0xFFFF0000u)) >> 16);
        *(ushort4*)&oh[obase] = hv;
        *(ushort4*)&ol[obase] = lv;
    }
}

// ---------------------------------------------------------------------------
// Transpose + split: W[K][Ntot] (cols n0..n0+Nc) -> Th/Tl [Nc][K] bf16
// ---------------------------------------------------------------------------
__global__ __launch_bounds__(256) void transpose_split_k(const float* __restrict__ W,
                                                         ushort* __restrict__ Th,
                                                         ushort* __restrict__ Tl,
                                                         int K, int Ntot, int n0) {
    __shared__ float t[64][65];
    int tid = threadIdx.x;
    int nt = blockIdx.x * 64;
    int kt = blockIdx.y * 64;
#pragma unroll
    for (int p = 0; p < 4; ++p) {
        int idx = tid + p * 256;
        int kk = idx >> 4;
        int nn = (idx & 15) * 4;
        float4 v = *(const float4*)&W[(size_t)(kt + kk) * Ntot + n0 + nt + nn];
        t[nn + 0][kk] = v.x;
        t[nn + 1][kk] = v.y;
        t[nn + 2][kk] = v.z;
        t[nn + 3][kk] = v.w;
    }
    __syncthreads();
#pragma unroll
    for (int p = 0; p < 4; ++p) {
        int idx = tid + p * 256;
        int nn = idx >> 4;
        int kk = (idx & 15) * 4;
        ushort4 hv, lv;
        float a0 = t[nn][kk + 0], a1 = t[nn][kk + 1], a2 = t[nn][kk + 2], a3 = t[nn][kk + 3];
        hv.x = f2bf(a0); lv.x = f2bf(a0 - bf2f(hv.x));
        hv.y = f2bf(a1); lv.y = f2bf(a1 - bf2f(hv.y));
        hv.z = f2bf(a2); lv.z = f2bf(a2 - bf2f(hv.z));
        hv.w = f2bf(a3); lv.w = f2bf(a3 - bf2f(hv.w));
        size_t o = (size_t)(nt + nn) * K + kt + kk;
        *(ushort4*)&Th[o] = hv;
        *(ushort4*)&Tl[o] = lv;
    }
}

// ---------------------------------------------------------------------------
// bf16x3 compensated MFMA GEMM (verified last round; unchanged).
// ---------------------------------------------------------------------------
template <int MODE>
__global__ __launch_bounds__(256, 3) void gemm_bf16x3(
    const ushort* __restrict__ Ah, const ushort* __restrict__ Al,
    const ushort* __restrict__ Bh, const ushort* __restrict__ Bl,
    const float* res, const float* __restrict__ gbuf,
    float* C, ushort* __restrict__ Dh, ushort* __restrict__ Dl,
    int M, int N, int K) {
    __shared__ __align__(16) ushort sA[2 * 64 * 32];
    __shared__ __align__(16) ushort sB[2 * 128 * 32];

    unsigned nbx = gridDim.x;
    unsigned flat = blockIdx.y * nbx + blockIdx.x;
    unsigned cpx = (nbx * gridDim.y) >> 3;
    unsigned sflat = (flat & 7u) * cpx + (flat >> 3);
    int bx = (int)(sflat % nbx);
    int by = (int)(sflat / nbx);
    int bm = by * 64, bn = bx * 128;

    int tid = threadIdx.x;
    int lane = tid & 63, wave = tid >> 6;

    int srow = tid >> 2;
    int sk = (tid & 3) * 8;
    const ushort* gAh = Ah + (size_t)(bm + srow) * K + sk;
    const ushort* gAl = Al + (size_t)(bm + srow) * K + sk;
    const ushort* gB0h = Bh + (size_t)(bn + srow) * K + sk;
    const ushort* gB0l = Bl + (size_t)(bn + srow) * K + sk;
    const ushort* gB1h = Bh + (size_t)(bn + 64 + srow) * K + sk;
    const ushort* gB1l = Bl + (size_t)(bn + 64 + srow) * K + sk;
    ushort* lAh = sA + tid * 8;
    ushort* lAl = sA + 2048 + tid * 8;
    ushort* lB0h = sB + tid * 8;
    ushort* lB1h = sB + 2048 + tid * 8;
    ushort* lB0l = sB + 4096 + tid * 8;
    ushort* lB1l = sB + 6144 + tid * 8;

    int r = lane & 15, kq = lane >> 4;
    const ushort* pA = sA + r * 32 + kq * 8;
    const ushort* pB = sB + (wave * 32 + r) * 32 + kq * 8;

    f32x4 acc[4][2] = {};

    for (int k0 = 0; k0 < K; k0 += 32) {
        glds16(gAh, lAh);
        glds16(gAl, lAl);
        glds16(gB0h, lB0h);
        glds16(gB1h, lB1h);
        glds16(gB0l, lB0l);
        glds16(gB1l, lB1l);
        gAh += 32; gAl += 32; gB0h += 32; gB0l += 32; gB1h += 32; gB1l += 32;
        __syncthreads();

        bf16x8 ah[4], al[4], bh[2], bl[2];
#pragma unroll
        for (int mi = 0; mi < 4; ++mi) {
            ah[mi] = *(const bf16x8*)(pA + mi * 512);
            al[mi] = *(const bf16x8*)(pA + 2048 + mi * 512);
        }
#pragma unroll
        for (int ni = 0; ni < 2; ++ni) {
            bh[ni] = *(const bf16x8*)(pB + ni * 512);
            bl[ni] = *(const bf16x8*)(pB + 4096 + ni * 512);
        }
#pragma unroll
        for (int mi = 0; mi < 4; ++mi)
#pragma unroll
            for (int ni = 0; ni < 2; ++ni) {
                acc[mi][ni] = __builtin_amdgcn_mfma_f32_16x16x32_bf16(ah[mi], bh[ni], acc[mi][ni], 0, 0, 0);
                acc[mi][ni] = __builtin_amdgcn_mfma_f32_16x16x32_bf16(al[mi], bh[ni], acc[mi][ni], 0, 0, 0);
                acc[mi][ni] = __builtin_amdgcn_mfma_f32_16x16x32_bf16(ah[mi], bl[ni], acc[mi][ni], 0, 0, 0);
            }
        __syncthreads();
    }

    int c0 = bn + wave * 32 + (lane & 15);
    int r0 = bm + (lane >> 4) * 4;
#pragma unroll
    for (int mi = 0; mi < 4; ++mi)
#pragma unroll
        for (int ni = 0; ni < 2; ++ni)
#pragma unroll
            for (int j = 0; j < 4; ++j) {
                int row = r0 + mi * 16 + j;
                int col = c0 + ni * 16;
                size_t idx = (size_t)row * N + col;
                float val = acc[mi][ni][j];
                if (MODE == 0) {
                    if (res) val += res[idx];
                    C[idx] = val;
                } else {
                    float gv = gbuf[idx];
                    float dv = gv / (1.0f + expf(-gv)) * val;
                    ushort hh = f2bf(dv);
                    Dh[idx] = hh;
                    Dl[idx] = f2bf(dv - bf2f(hh));
                }
            }
}

// ---------------------------------------------------------------------------
// Per-head RMSNorm (over HD=128) + RoPE, in place.
// ---------------------------------------------------------------------------
__global__ __launch_bounds__(128) void qk_norm_rope_k(float* __restrict__ qk,
                                                      const float* __restrict__ nw,
                                                      const int* __restrict__ positions,
                                                      int nheads) {
    int s = blockIdx.x;
    int h = blockIdx.y;
    int d = threadIdx.x;
    float* row = qk + ((size_t)s * nheads + h) * HD;
    __shared__ float buf[HD];
    __shared__ float red[HD];
    float v = row[d];
    red[d] = v * v;
    __syncthreads();
    for (int off = 64; off > 0; off >>= 1) {
        if (d < off) red[d] += red[d + off];
        __syncthreads();
    }
    float r = rsqrtf(red[0] / (float)HD + EPSV);
    float nv = v * r * nw[d];
    buf[d] = nv;
    __syncthreads();
    float pos = (float)positions[s];
    int d2 = d & 63;
    float inv_freq = expf(-((float)(2 * d2) / 128.0f) * 13.815510557964274f);
    float freq = pos * inv_freq;
    float c, sn;
    sincosf(freq, &sn, &c);
    float rot = (d < 64) ? -buf[d + 64] : buf[d - 64];
    row[d] = nv * c + rot * sn;
}

// ---------------------------------------------------------------------------
// MFMA flash attention, bf16x3 compensated.
//   Block: 4 waves x 16 q-rows (TQ=64), one head. KV tile = 64.
//   K staged [kv][128] bf16 hi/lo (d pre-swizzled in global: d^=(s&7)<<3);
//   V^T staged [d][64] hi/lo (s pre-swizzled: s^=(d&7)<<3).
//   QK^T: 3-term MFMA 16x16x32; softmax in-register (16-lane shfl groups);
//   P split hi/lo into per-wave LDS region overlaid on dead sKh; PV 3-term.
//   LDS 64.5 KB -> 2 blocks/CU.
// ---------------------------------------------------------------------------
#define ATQ 64
#define ATK 64

__global__ __launch_bounds__(256, 2) void attn_mfma_k(
    const ushort* __restrict__ Qhg, const ushort* __restrict__ Qlg,
    const ushort* __restrict__ Khg, const ushort* __restrict__ Klg,
    const ushort* __restrict__ Vhg, const ushort* __restrict__ Vlg,
    const int* __restrict__ keys_idxs, const int* __restrict__ hs_idxs,
    float* __restrict__ ctx) {
    __shared__ __align__(16) ushort sKh[64 * 128];   // also P overlay (4 x 2048)
    __shared__ __align__(16) ushort sKl[64 * 128];
    __shared__ __align__(16) ushort sVh[128 * 64];
    __shared__ __align__(16) ushort sVl[128 * 64];
    __shared__ int kidx[ATK];
    __shared__ int qpos[ATQ];

    int bx = blockIdx.x;
    int qt = (bx & 1) ? (31 - (bx >> 1)) : (bx >> 1);   // heavy/light pairing
    int h = blockIdx.y;
    int kvh = h >> 1;
    int tid = threadIdx.x;
    int lane = tid & 63, wv = tid >> 6;
    int q0 = qt * ATQ;
    int r = lane & 15, kq = lane >> 4;
    int xorv = (lane & 7) << 3;
    const float scale = 0.088388347648318447f;

    // Q fragments (A operand): row = lane&15, k = kq*8 (+32 per kstep)
    bf16x8 qh[4], ql[4];
    {
        const ushort* qb = Qhg + ((size_t)(q0 + wv * 16 + r) * NHEADS + h) * HD + kq * 8;
        const ushort* qb2 = Qlg + ((size_t)(q0 + wv * 16 + r) * NHEADS + h) * HD + kq * 8;
#pragma unroll
        for (int ks = 0; ks < 4; ++ks) {
            qh[ks] = *(const bf16x8*)(qb + ks * 32);
            ql[ks] = *(const bf16x8*)(qb2 + ks * 32);
        }
    }
    if (tid < ATQ) qpos[tid] = hs_idxs[q0 + tid];

    // staging base pointers (per-thread)
    const size_t kvstride = (size_t)NKVH * HD;   // 1024
    const ushort* gKh = Khg + ((size_t)(tid >> 4) * NKVH + kvh) * HD + (tid & 15) * 8;
    const ushort* gKl = Klg + ((size_t)(tid >> 4) * NKVH + kvh) * HD + (tid & 15) * 8;
    const ushort* gVh = Vhg + ((size_t)kvh * HD + (tid >> 3)) * S_LEN + (tid & 7) * 8;
    const ushort* gVl = Vlg + ((size_t)kvh * HD + (tid >> 3)) * S_LEN + (tid & 7) * 8;

    f32x4 o[8] = {};
    float m_run[4] = {-3.0e38f, -3.0e38f, -3.0e38f, -3.0e38f};
    float l_run[4] = {0.0f, 0.0f, 0.0f, 0.0f};

    __syncthreads();
    int hs_max = qpos[ATQ - 1];
    int qp[4];
#pragma unroll
    for (int j = 0; j < 4; ++j) qp[j] = qpos[wv * 16 + kq * 4 + j];

    for (int kt = 0; kt < S_LEN / ATK; ++kt) {
        int k0 = kt * ATK;
        if (keys_idxs[k0] > hs_max) break;   // uniform across block
        __syncthreads();   // previous tile fully consumed
        const size_t koff = (size_t)k0 * kvstride;
#pragma unroll
        for (int p = 0; p < 4; ++p) {
            glds16(gKh + koff + (size_t)p * 16 * kvstride, sKh + (tid + p * 256) * 8);
            glds16(gKl + koff + (size_t)p * 16 * kvstride, sKl + (tid + p * 256) * 8);
            glds16(gVh + k0 + (size_t)p * 32 * S_LEN, sVh + (tid + p * 256) * 8);
            glds16(gVl + k0 + (size_t)p * 32 * S_LEN, sVl + (tid + p * 256) * 8);
        }
        if (tid < ATK) kidx[tid] = keys_idxs[k0 + tid];
        __syncthreads();   // staged tiles resident (vmcnt drained by barrier)

        // ---- S = Q K^T (3-term) ----
        f32x4 sf[4] = {};
#pragma unroll
        for (int ks = 0; ks < 4; ++ks) {
            int kb = (ks * 32 + kq * 8) ^ xorv;
#pragma unroll
            for (int f = 0; f < 4; ++f) {
                bf16x8 kh = *(const bf16x8*)(sKh + (f * 16 + r) * 128 + kb);
                bf16x8 kl = *(const bf16x8*)(sKl + (f * 16 + r) * 128 + kb);
                sf[f] = __builtin_amdgcn_mfma_f32_16x16x32_bf16(qh[ks], kh, sf[f], 0, 0, 0);
                sf[f] = __builtin_amdgcn_mfma_f32_16x16x32_bf16(ql[ks], kh, sf[f], 0, 0, 0);
                sf[f] = __builtin_amdgcn_mfma_f32_16x16x32_bf16(qh[ks], kl, sf[f], 0, 0, 0);
            }
        }

        // ---- online softmax (per lane: 4 rows j x 4 cols f; kv = f*16+r) ----
        int kj[4];
#pragma unroll
        for (int f = 0; f < 4; ++f) kj[f] = kidx[f * 16 + r];
        float alj[4];
#pragma unroll
        for (int j = 0; j < 4; ++j) {
#pragma unroll
            for (int f = 0; f < 4; ++f)
                sf[f][j] = sf[f][j] * scale + ((kj[f] <= qp[j]) ? 0.0f : -1.0e9f);
            float m0 = fmaxf(fmaxf(sf[0][j], sf[1][j]), fmaxf(sf[2][j], sf[3][j]));
#pragma unroll
            for (int off = 1; off < 16; off <<= 1) m0 = fmaxf(m0, __shfl_xor(m0, off));
            float mn = fmaxf(m_run[j], m0);
            alj[j] = __expf(m_run[j] - mn);
            m_run[j] = mn;
            float rsum = 0.0f;
#pragma unroll
            for (int f = 0; f < 4; ++f) {
                sf[f][j] = __expf(sf[f][j] - mn);
                rsum += sf[f][j];
            }
#pragma unroll
            for (int off = 1; off < 16; off <<= 1) rsum += __shfl_xor(rsum, off);
            l_run[j] = l_run[j] * alj[j] + rsum;
        }
#pragma unroll
        for (int df = 0; df < 8; ++df)
#pragma unroll
            for (int j = 0; j < 4; ++j) o[df][j] *= alj[j];

        __syncthreads();   // all waves done reading sKh -> safe to overlay P

        // ---- P split hi/lo -> per-wave LDS region (overlaid on sKh) ----
        ushort* sPh = sKh + wv * 2048;
        ushort* sPl = sPh + 1024;
#pragma unroll
        for (int j = 0; j < 4; ++j) {
            int qloc = kq * 4 + j;
            int swz = (qloc & 7) << 3;
            int rowb = qloc * 64;
#pragma unroll
            for (int f = 0; f < 4; ++f) {
                float pv = sf[f][j];
                unsigned u = __float_as_uint(pv);
                float hi = __uint_as_float(u & 0xFFFF0000u);
                int a = rowb + ((f * 16 + r) ^ swz);
                sPh[a] = (ushort)(u >> 16);
                sPl[a] = (ushort)(__float_as_uint(pv - hi) >> 16);
            }
        }

        // ---- O += P V (3-term); A = own-wave P (no barrier needed) ----
#pragma unroll
        for (int kv0 = 0; kv0 < 2; ++kv0) {
            int kb = (kv0 * 32 + kq * 8) ^ xorv;
            bf16x8 pah = *(const bf16x8*)(sPh + r * 64 + kb);
            bf16x8 pal = *(const bf16x8*)(sPl + r * 64 + kb);
#pragma unroll
            for (int df = 0; df < 8; ++df) {
                bf16x8 vh = *(const bf16x8*)(sVh + (df * 16 + r) * 64 + kb);
                bf16x8 vl = *(const bf16x8*)(sVl + (df * 16 + r) * 64 + kb);
                o[df] = __builtin_amdgcn_mfma_f32_16x16x32_bf16(pah, vh, o[df], 0, 0, 0);
                o[df] = __builtin_amdgcn_mfma_f32_16x16x32_bf16(pal, vh, o[df], 0, 0, 0);
                o[df] = __builtin_amdgcn_mfma_f32_16x16x32_bf16(pah, vl, o[df], 0, 0, 0);
            }
        }
    }

    // epilogue: normalize + scatter store (C layout: col=lane&15, row=kq*4+j)
#pragma unroll
    for (int j = 0; j < 4; ++j) {
        float invl = 1.0f / l_run[j];
        int qg = q0 + wv * 16 + kq * 4 + j;
#pragma unroll
        for (int df = 0; df < 8; ++df) {
            int d = df * 16 + r;
            ctx[((size_t)qg * NHEADS + h) * HD + d] = o[df][j] * invl;
        }
    }
}

// ---------------------------------------------------------------------------
// Importance: softmax (no mask) of last q row vs all keys, per head. (fp32)
// ---------------------------------------------------------------------------
__global__ __launch_bounds__(256) void importance_scores_k(const float* __restrict__ q,
                                                           const float* __restrict__ k,
                                                           float* __restrict__ imp_ws) {
    int h = blockIdx.x;
    int kv = h >> 1;
    int tid = threadIdx.x;
    __shared__ float qrow[HD];
    __shared__ float sc[S_LEN];
    __shared__ float red[256];
    const float* qp = q + ((size_t)(S_LEN - 1) * NHEADS + h) * HD;
    if (tid < HD) qrow[tid] = qp[tid];
    __syncthreads();
    const float scale = 0.088388347648318447f;
    float lmax = -3.0e38f;
#pragma unroll
    for (int rep = 0; rep < 8; ++rep) {
        int j = tid + rep * 256;
        const float* kp = k + ((size_t)j * NKVH + kv) * HD;
        float dot = 0.0f;
        for (int d = 0; d < HD; ++d) dot += qrow[d] * kp[d];
        float sval = dot * scale;
        sc[j] = sval;
        lmax = fmaxf(lmax, sval);
    }
    red[tid] = lmax;
    __syncthreads();
    for (int off = 128; off > 0; off >>= 1) {
        if (tid < off) red[tid] = fmaxf(red[tid], red[tid + off]);
        __syncthreads();
    }
    float m = red[0];
    __syncthreads();
    float lsum = 0.0f;
    float evals[8];
#pragma unroll
    for (int rep = 0; rep < 8; ++rep) {
        int j = tid + rep * 256;
        float e = expf(sc[j] - m);
        evals[rep] = e;
        lsum += e;
    }
    red[tid] = lsum;
    __syncthreads();
    for (int off = 128; off > 0; off >>= 1) {
        if (tid < off) red[tid] += red[tid + off];
        __syncthreads();
    }
    float inv = 1.0f / red[0];
#pragma unroll
    for (int rep = 0; rep < 8; ++rep) {
        int j = tid + rep * 256;
        imp_ws[(size_t)h * S_LEN + j] = evals[rep] * inv;
    }
}

__global__ __launch_bounds__(256) void importance_combine_k(const float* __restrict__ imp_ws,
                                                            float* __restrict__ out) {
    int j = blockIdx.x * 256 + threadIdx.x;
    float sum = 0.0f;
    for (int h = 0; h < NHEADS; ++h) sum += imp_ws[(size_t)h * S_LEN + j];
    out[j] = (j == S_LEN - 1) ? 3.0e38f : sum * (1.0f / NHEADS);
}

// ---------------------------------------------------------------------------
extern "C" void kernel_launch(void* const* d_in, const int* in_sizes, int n_in,
                              void* d_out, int out_size, void* d_ws, size_t ws_size,
                              hipStream_t stream) {
    const float* hidden    = (const float*)d_in[0];
    const int*   keys_idxs = (const int*)d_in[2];
    const int*   hs_idxs   = (const int*)d_in[3];
    const int*   positions = (const int*)d_in[4];
    const float* ln_in_w   = (const float*)d_in[5];
    const float* q_w       = (const float*)d_in[6];
    const float* k_w       = (const float*)d_in[7];
    const float* v_w       = (const float*)d_in[8];
    const float* q_norm_w  = (const float*)d_in[9];
    const float* k_norm_w  = (const float*)d_in[10];
    const float* o_w       = (const float*)d_in[11];
    const float* ln_post_w = (const float*)d_in[12];
    const float* gate_w    = (const float*)d_in[13];
    const float* up_w      = (const float*)d_in[14];
    const float* down_w    = (const float*)d_in[15];

    float* out = (float*)d_out;
    float* ws = (float*)d_ws;
    const size_t MF = 1024ull * 1024;

    // Region plan (floats; peak 20 MF = 80 MB):
    //  [0,4M)    Xh/Xl bf16        -> Qbh/Qbl bf16 (X dead after v GEMM)
    //  [4M,8M)   Wh/Wl bf16        -> imp scratch -> Kbh/Kbl + Vth/Vtl -> Wh/Wl again
    //  [8M,12M)  q fp32            -> Ch/Cl bf16 -> g chunk fp32
    //  [12M,14M) k fp32            \_ h fp32 -> D chunk Dh/Dl
    //  [14M,16M) v fp32            /
    //  [16M,20M) ctx fp32          -> Yh/Yl bf16
    ushort* Xh = (ushort*)(ws);
    ushort* Xl = (ushort*)(ws + 2 * MF);
    ushort* Wh = (ushort*)(ws + 4 * MF);
    ushort* Wl = (ushort*)(ws + 6 * MF);
    float*  qb  = ws + 8 * MF;
    float*  kbf = ws + 12 * MF;
    float*  vbf = ws + 14 * MF;
    float*  ctx = ws + 16 * MF;
    ushort* Qbh = (ushort*)(ws);
    ushort* Qbl = (ushort*)(ws + 2 * MF);
    float*  imp = ws + 4 * MF;
    ushort* Kbh = (ushort*)(ws + 4 * MF);
    ushort* Kbl = (ushort*)(ws + 5 * MF);
    ushort* Vth = (ushort*)(ws + 6 * MF);
    ushort* Vtl = (ushort*)(ws + 7 * MF);
    ushort* Ch = (ushort*)(ws + 8 * MF);
    ushort* Cl = (ushort*)(ws + 10 * MF);
    float*  hb = ws + 12 * MF;
    ushort* Yh = (ushort*)(ws + 16 * MF);
    ushort* Yl = (ushort*)(ws + 18 * MF);
    float*  gb = ws + 8 * MF;
    ushort* Dh = (ushort*)(ws + 12 * MF);
    ushort* Dl = (ushort*)(ws + 14 * MF);

    // 1. x = rms(hidden) -> bf16 split
    rmsnorm_split_k<<<S_LEN, 256, 0, stream>>>(hidden, ln_in_w, Xh, Xl);

    // 2. q/k/v projections (MFMA bf16x3)
    transpose_split_k<<<dim3(32, 32), 256, 0, stream>>>(q_w, Wh, Wl, HDIM, HDIM, 0);
    gemm_bf16x3<0><<<dim3(HDIM / 128, S_LEN / 64), 256, 0, stream>>>(
        Xh, Xl, Wh, Wl, nullptr, nullptr, qb, nullptr, nullptr, S_LEN, HDIM, HDIM);

    transpose_split_k<<<dim3(16, 32), 256, 0, stream>>>(k_w, Wh, Wl, HDIM, 1024, 0);
    gemm_bf16x3<0><<<dim3(1024 / 128, S_LEN / 64), 256, 0, stream>>>(
        Xh, Xl, Wh, Wl, nullptr, nullptr, kbf, nullptr, nullptr, S_LEN, 1024, HDIM);

    transpose_split_k<<<dim3(16, 32), 256, 0, stream>>>(v_w, Wh, Wl, HDIM, 1024, 0);
    gemm_bf16x3<0><<<dim3(1024 / 128, S_LEN / 64), 256, 0, stream>>>(
        Xh, Xl, Wh, Wl, nullptr, nullptr, vbf, nullptr, nullptr, S_LEN, 1024, HDIM);

    // 3. per-head norm + rope (fp32, in place)
    qk_norm_rope_k<<<dim3(S_LEN, NHEADS), 128, 0, stream>>>(qb, q_norm_w, positions, NHEADS);
    qk_norm_rope_k<<<dim3(S_LEN, NKVH), 128, 0, stream>>>(kbf, k_norm_w, positions, NKVH);

    // 4. importance (fp32 q,k; before conv_k overwrites its scratch region)
    importance_scores_k<<<NHEADS, 256, 0, stream>>>(qb, kbf, imp);
    importance_combine_k<<<S_LEN / 256, 256, 0, stream>>>(imp, out + (size_t)S_LEN * HDIM);

    // 5. convert q/k/v to bf16 hi/lo attention layouts
    split_k<<<(S_LEN * NHEADS * HD) / 256, 256, 0, stream>>>(qb, Qbh, Qbl, S_LEN * NHEADS * HD);
    conv_k_swz_k<<<(S_LEN * NKVH * HD) / 256, 256, 0, stream>>>(kbf, Kbh, Kbl);
    conv_vt_k<<<dim3(S_LEN / 64, HD / 64, NKVH), 256, 0, stream>>>(vbf, Vth, Vtl);

    // 6. MFMA flash attention -> ctx
    attn_mfma_k<<<dim3(S_LEN / ATQ, NHEADS), 256, 0, stream>>>(
        Qbh, Qbl, Kbh, Kbl, Vth, Vtl, keys_idxs, hs_idxs, ctx);

    // 7. h = hidden + ctx @ o_w
    split_k<<<(S_LEN * HDIM) / 256, 256, 0, stream>>>(ctx, Ch, Cl, S_LEN * HDIM);
    transpose_split_k<<<dim3(32, 32), 256, 0, stream>>>(o_w, Wh, Wl, HDIM, HDIM, 0);
    gemm_bf16x3<0><<<dim3(HDIM / 128, S_LEN / 64), 256, 0, stream>>>(
        Ch, Cl, Wh, Wl, hidden, nullptr, hb, S_LEN ? nullptr : nullptr, nullptr, S_LEN, HDIM, HDIM);

    // 8. out = h (residual base for chunked down-proj accumulation)
    hipMemcpyAsync(out, hb, (size_t)S_LEN * HDIM * sizeof(float),
                   hipMemcpyDeviceToDevice, stream);

    // 9. y = rms(h) -> bf16 split
    rmsnorm_split_k<<<S_LEN, 256, 0, stream>>>(hb, ln_post_w, Yh, Yl);

    // 10. MLP in three FF-chunks of 2048 (fused silu epilogue)
    for (int c = 0; c < 3; ++c) {
        transpose_split_k<<<dim3(32, 32), 256, 0, stream>>>(gate_w, Wh, Wl, HDIM, FFDIM, c * 2048);
        gemm_bf16x3<0><<<dim3(16, 32), 256, 0, stream>>>(
            Yh, Yl, Wh, Wl, nullptr, nullptr, gb, nullptr, nullptr, S_LEN, 2048, HDIM);
        transpose_split_k<<<dim3(32, 32), 256, 0, stream>>>(up_w, Wh, Wl, HDIM, FFDIM, c * 2048);
        gemm_bf16x3<1><<<dim3(16, 32), 256, 0, stream>>>(
            Yh, Yl, Wh, Wl, nullptr, gb, nullptr, Dh, Dl, S_LEN, 2048, HDIM);
        transpose_split_k<<<dim3(32, 32), 256, 0, stream>>>(
            down_w + (size_t)c * 2048 * HDIM, Wh, Wl, 2048, HDIM, 0);
        gemm_bf16x3<0><<<dim3(16, 32), 256, 0, stream>>>(
            Dh, Dl, Wh, Wl, out, nullptr, out, nullptr, nullptr, S_LEN, HDIM, 2048);
    }
}